// Round 1
// baseline (1524.095 us; speedup 1.0000x reference)
//
#include <hip/hip_runtime.h>
#include <math.h>

// GATGuard: 3-layer GAT with cosine-sim attention, threshold 0.1, L1 row norm,
// exp weights, degree-based self-loop weight. All fp32.
// N=50000, E=800000, dims: 128 -> (4x64=256) -> (4x64=256) -> 16.

static inline int cdiv(int a, int b){ return (a + b - 1) / b; }

// ---------------- CSR build (from row[]) ----------------

__global__ void count_kernel(const int* __restrict__ row, int* __restrict__ cnt, int E){
  int e = blockIdx.x * blockDim.x + threadIdx.x;
  if (e < E) atomicAdd(&cnt[row[e]], 1);
}

__global__ void scan_kernel(const int* __restrict__ cnt, int* __restrict__ offs, int n){
  // single block of 1024 threads, sequential chunks with carried sum
  __shared__ int tmp[1024];
  __shared__ int carry_s;
  int tid = threadIdx.x;
  if (tid == 0) carry_s = 0;
  __syncthreads();
  for (int base = 0; base < n; base += 1024){
    int v = (base + tid < n) ? cnt[base + tid] : 0;
    tmp[tid] = v;
    __syncthreads();
    for (int off = 1; off < 1024; off <<= 1){
      int t = (tid >= off) ? tmp[tid - off] : 0;
      __syncthreads();
      tmp[tid] += t;
      __syncthreads();
    }
    if (base + tid < n) offs[base + tid] = carry_s + tmp[tid] - v;  // exclusive
    __syncthreads();
    if (tid == 0) carry_s += tmp[1023];
    __syncthreads();
  }
  if (tid == 0) offs[n] = carry_s;
}

__global__ void initcur_kernel(const int* __restrict__ offs, int* __restrict__ cur, int n){
  int i = blockIdx.x * blockDim.x + threadIdx.x;
  if (i < n) cur[i] = offs[i];
}

__global__ void scatter_kernel(const int* __restrict__ row, int* __restrict__ cur,
                               int* __restrict__ eidx, int E){
  int e = blockIdx.x * blockDim.x + threadIdx.x;
  if (e < E){
    int p = atomicAdd(&cur[row[e]], 1);
    eidx[p] = e;
  }
}

// ---------------- attention coefficients ----------------

template<int D>
__global__ void invnorm_kernel(const float* __restrict__ x, float* __restrict__ invn, int N){
  // one wave per node
  int n = blockIdx.x * 4 + (threadIdx.x >> 6);
  int lane = threadIdx.x & 63;
  if (n >= N) return;
  const float* xr = x + (size_t)n * D;
  float ss;
  if constexpr (D == 256){
    float4 a = ((const float4*)xr)[lane];
    ss = a.x*a.x + a.y*a.y + a.z*a.z + a.w*a.w;
  } else {
    float2 a = ((const float2*)xr)[lane];
    ss = a.x*a.x + a.y*a.y;
  }
  for (int off = 32; off; off >>= 1) ss += __shfl_xor(ss, off);
  if (lane == 0) invn[n] = 1.0f / fmaxf(sqrtf(ss), 1e-12f);
}

template<int D>
__global__ void edge_sim_kernel(const float* __restrict__ x, const float* __restrict__ invn,
                                const int* __restrict__ row, const int* __restrict__ col,
                                float* __restrict__ sim, float* __restrict__ rowsum,
                                float* __restrict__ deg, int E){
  // one wave per edge
  int e = (blockIdx.x * blockDim.x + threadIdx.x) >> 6;
  int lane = threadIdx.x & 63;
  if (e >= E) return;
  int r = row[e], c = col[e];
  const float* xr = x + (size_t)r * D;
  const float* xc = x + (size_t)c * D;
  float s;
  if constexpr (D == 256){
    float4 a = ((const float4*)xr)[lane];
    float4 b = ((const float4*)xc)[lane];
    s = a.x*b.x + a.y*b.y + a.z*b.z + a.w*b.w;
  } else {
    float2 a = ((const float2*)xr)[lane];
    float2 b = ((const float2*)xc)[lane];
    s = a.x*b.x + a.y*b.y;
  }
  for (int off = 32; off; off >>= 1) s += __shfl_xor(s, off);
  if (lane == 0){
    s *= invn[r] * invn[c];
    if (s < 0.1f) s = 0.0f;          // threshold; survivors are > 0
    sim[e] = s;
    if (s != 0.0f){
      atomicAdd(&rowsum[r], s);      // |sim| == sim (positive)
      atomicAdd(&deg[r], 1.0f);
    }
  }
}

__global__ void wself_kernel(float* __restrict__ rowsum, const float* __restrict__ deg,
                             float* __restrict__ wself, int N){
  int i = blockIdx.x * blockDim.x + threadIdx.x;
  if (i < N){
    wself[i] = expf(1.0f / (deg[i] + 1.0f));
    float rs = rowsum[i];
    rowsum[i] = (rs > 0.0f) ? 1.0f / rs : 0.0f;  // becomes inv_rowsum
  }
}

__global__ void wedge_kernel(float* __restrict__ sim, const int* __restrict__ row,
                             const float* __restrict__ inv_rowsum, int E){
  int e = blockIdx.x * blockDim.x + threadIdx.x;
  if (e < E){
    float s = sim[e];
    sim[e] = (s > 0.0f) ? expf(s * inv_rowsum[row[e]]) : 0.0f;  // becomes w_edge
  }
}

// ---------------- projection z = einsum('nd,hdo->nho') ----------------

template<int D>
__global__ void proj_kernel(const float* __restrict__ x, const float* __restrict__ W,
                            float* __restrict__ z, int N){
  // block = 256 threads, 8 nodes per block, 256 outputs (4 heads x 64)
  __shared__ float xs[8][D];
  int tid = threadIdx.x;
  int n0 = blockIdx.x * 8;
  for (int i = tid; i < 8 * D; i += 256){
    int nl = i / D, d = i % D;
    int n = n0 + nl;
    xs[nl][d] = (n < N) ? x[(size_t)n * D + d] : 0.0f;
  }
  __syncthreads();
  int h = tid >> 6, o = tid & 63;
  const float* Wp = W + (size_t)h * D * 64 + o;
  float acc[8];
  #pragma unroll
  for (int i = 0; i < 8; i++) acc[i] = 0.0f;
  for (int d = 0; d < D; d++){
    float w = Wp[(size_t)d * 64];
    #pragma unroll
    for (int i = 0; i < 8; i++) acc[i] += xs[i][d] * w;
  }
  #pragma unroll
  for (int i = 0; i < 8; i++){
    int n = n0 + i;
    if (n < N) z[(size_t)n * 256 + tid] = acc[i];
  }
}

__global__ void proj16_kernel(const float* __restrict__ x, const float* __restrict__ W,
                              float* __restrict__ z, int N){
  // layer 2: D=256, 16 outputs. block = 16 nodes x 16 outputs
  __shared__ float xs[16][256];   // 16 KB
  __shared__ float wsh[256 * 16]; // 16 KB
  int tid = threadIdx.x;
  int n0 = blockIdx.x * 16;
  for (int i = tid; i < 16 * 256; i += 256){
    int nl = i >> 8, d = i & 255;
    int n = n0 + nl;
    xs[nl][d] = (n < N) ? x[(size_t)n * 256 + d] : 0.0f;
  }
  for (int i = tid; i < 256 * 16; i += 256) wsh[i] = W[i];
  __syncthreads();
  int nl = tid >> 4, o = tid & 15;
  float acc = 0.0f;
  for (int d = 0; d < 256; d++) acc += xs[nl][d] * wsh[d * 16 + o];
  int n = n0 + nl;
  if (n < N) z[(size_t)n * 16 + o] = acc;
}

// ---------------- aggregation ----------------

template<bool ACT>
__global__ void agg256_kernel(const float* __restrict__ z, const float* __restrict__ wedge,
                              const float* __restrict__ wself, const int* __restrict__ offs,
                              const int* __restrict__ eidx, const int* __restrict__ col,
                              float* __restrict__ out, int N){
  // one block (256 threads) per node; thread t owns output channel t
  __shared__ float ws[256];
  __shared__ int   cs[256];
  int n = blockIdx.x;
  int tid = threadIdx.x;
  int s = offs[n], e_end = offs[n + 1];
  float acc = wself[n] * z[(size_t)n * 256 + tid];
  for (int base = s; base < e_end; base += 256){
    int k = base + tid;
    if (k < e_end){
      int e = eidx[k];
      ws[tid] = wedge[e];
      cs[tid] = col[e];
    }
    __syncthreads();
    int cnt = min(256, e_end - base);
    for (int t = 0; t < cnt; t++){
      float w = ws[t];
      if (w != 0.0f) acc += w * z[(size_t)cs[t] * 256 + tid];
    }
    __syncthreads();
  }
  if (ACT) acc = (acc > 0.0f) ? acc : 0.01f * acc;
  out[(size_t)n * 256 + tid] = acc;
}

__global__ void agg16_kernel(const float* __restrict__ z, const float* __restrict__ wedge,
                             const float* __restrict__ wself, const int* __restrict__ offs,
                             const int* __restrict__ eidx, const int* __restrict__ col,
                             float* __restrict__ out, int N){
  int tid = threadIdx.x;
  int n = blockIdx.x * 16 + (tid >> 4);
  int o = tid & 15;
  if (n >= N) return;
  float acc = wself[n] * z[(size_t)n * 16 + o];
  int s = offs[n], e_end = offs[n + 1];
  for (int k = s; k < e_end; k++){
    int e = eidx[k];
    float w = wedge[e];
    if (w != 0.0f) acc += w * z[(size_t)col[e] * 16 + o];
  }
  out[(size_t)n * 16 + o] = acc;  // no activation on last layer
}

// ---------------- launch ----------------

extern "C" void kernel_launch(void* const* d_in, const int* in_sizes, int n_in,
                              void* d_out, int out_size, void* d_ws, size_t ws_size,
                              hipStream_t stream){
  const float* x  = (const float*)d_in[0];
  const float* W0 = (const float*)d_in[1];
  const float* W1 = (const float*)d_in[2];
  const float* W2 = (const float*)d_in[3];
  const int*   row = (const int*)d_in[4];
  const int*   col = (const int*)d_in[5];
  const int N = in_sizes[0] / 128;
  const int E = in_sizes[4];
  float* out = (float*)d_out;

  // workspace carve-up (~110 MB)
  float* p = (float*)d_ws;
  float* hbuf   = p; p += (size_t)N * 256;
  float* zbuf   = p; p += (size_t)N * 256;
  float* simbuf = p; p += E;          // sim -> w_edge in place
  float* rowsum = p; p += N;          // rowsum -> inv_rowsum in place
  float* degb   = p; p += N;
  float* wselfb = p; p += N;
  float* invn   = p; p += N;
  int* cnt  = (int*)p;
  int* offs = cnt + N;
  int* cur  = offs + N + 1;
  int* eidx = cur + N;

  // ---- CSR build (row/col static per call) ----
  hipMemsetAsync(cnt, 0, sizeof(int) * N, stream);
  count_kernel<<<cdiv(E, 256), 256, 0, stream>>>(row, cnt, E);
  scan_kernel<<<1, 1024, 0, stream>>>(cnt, offs, N);
  initcur_kernel<<<cdiv(N, 256), 256, 0, stream>>>(offs, cur, N);
  scatter_kernel<<<cdiv(E, 256), 256, 0, stream>>>(row, cur, eidx, E);

  // ---- Layer 0: in=x (D=128), W0[4,128,64], act ----
  hipMemsetAsync(rowsum, 0, sizeof(float) * N, stream);
  hipMemsetAsync(degb,   0, sizeof(float) * N, stream);
  invnorm_kernel<128><<<cdiv(N, 4), 256, 0, stream>>>(x, invn, N);
  edge_sim_kernel<128><<<cdiv(E, 4), 256, 0, stream>>>(x, invn, row, col, simbuf, rowsum, degb, E);
  wself_kernel<<<cdiv(N, 256), 256, 0, stream>>>(rowsum, degb, wselfb, N);
  wedge_kernel<<<cdiv(E, 256), 256, 0, stream>>>(simbuf, row, rowsum, E);
  proj_kernel<128><<<cdiv(N, 8), 256, 0, stream>>>(x, W0, zbuf, N);
  agg256_kernel<true><<<N, 256, 0, stream>>>(zbuf, simbuf, wselfb, offs, eidx, col, hbuf, N);

  // ---- Layer 1: in=hbuf (D=256), W1[4,256,64], act ----
  hipMemsetAsync(rowsum, 0, sizeof(float) * N, stream);
  hipMemsetAsync(degb,   0, sizeof(float) * N, stream);
  invnorm_kernel<256><<<cdiv(N, 4), 256, 0, stream>>>(hbuf, invn, N);
  edge_sim_kernel<256><<<cdiv(E, 4), 256, 0, stream>>>(hbuf, invn, row, col, simbuf, rowsum, degb, E);
  wself_kernel<<<cdiv(N, 256), 256, 0, stream>>>(rowsum, degb, wselfb, N);
  wedge_kernel<<<cdiv(E, 256), 256, 0, stream>>>(simbuf, row, rowsum, E);
  proj_kernel<256><<<cdiv(N, 8), 256, 0, stream>>>(hbuf, W1, zbuf, N);
  agg256_kernel<true><<<N, 256, 0, stream>>>(zbuf, simbuf, wselfb, offs, eidx, col, hbuf, N);

  // ---- Layer 2: in=hbuf (D=256), W2[1,256,16], no act, out=d_out ----
  hipMemsetAsync(rowsum, 0, sizeof(float) * N, stream);
  hipMemsetAsync(degb,   0, sizeof(float) * N, stream);
  invnorm_kernel<256><<<cdiv(N, 4), 256, 0, stream>>>(hbuf, invn, N);
  edge_sim_kernel<256><<<cdiv(E, 4), 256, 0, stream>>>(hbuf, invn, row, col, simbuf, rowsum, degb, E);
  wself_kernel<<<cdiv(N, 256), 256, 0, stream>>>(rowsum, degb, wselfb, N);
  wedge_kernel<<<cdiv(E, 256), 256, 0, stream>>>(simbuf, row, rowsum, E);
  proj16_kernel<<<cdiv(N, 16), 256, 0, stream>>>(hbuf, W2, zbuf, N);
  agg16_kernel<<<cdiv(N, 16), 256, 0, stream>>>(zbuf, simbuf, wselfb, offs, eidx, col, out, N);
}

// Round 2
// 1289.523 us; speedup vs baseline: 1.1819x; 1.1819x over previous
//
#include <hip/hip_runtime.h>
#include <math.h>

// GATGuard: 3-layer GAT, cosine-sim attention (thresh 0.1), L1 row norm,
// exp weights, degree self-loop. fp32. N=50000, E=800000, 128->256->256->16.
//
// R2: CSR-ordered fused attention kernel (per-node block, LDS row staging,
// in-block rowsum/deg, survivor compaction), invnorm fused into agg epilogue.

static inline int cdiv(int a, int b){ return (a + b - 1) / b; }

// ---------------- CSR build (from row[]/col[]) ----------------

__global__ void count_kernel(const int* __restrict__ row, int* __restrict__ cnt, int E){
  int e = blockIdx.x * blockDim.x + threadIdx.x;
  if (e < E) atomicAdd(&cnt[row[e]], 1);
}

__global__ void scan_kernel(const int* __restrict__ cnt, int* __restrict__ offs, int n){
  __shared__ int tmp[1024];
  __shared__ int carry_s;
  int tid = threadIdx.x;
  if (tid == 0) carry_s = 0;
  __syncthreads();
  for (int base = 0; base < n; base += 1024){
    int v = (base + tid < n) ? cnt[base + tid] : 0;
    tmp[tid] = v;
    __syncthreads();
    for (int off = 1; off < 1024; off <<= 1){
      int t = (tid >= off) ? tmp[tid - off] : 0;
      __syncthreads();
      tmp[tid] += t;
      __syncthreads();
    }
    if (base + tid < n) offs[base + tid] = carry_s + tmp[tid] - v;  // exclusive
    __syncthreads();
    if (tid == 0) carry_s += tmp[1023];
    __syncthreads();
  }
  if (tid == 0) offs[n] = carry_s;
}

__global__ void initcur_kernel(const int* __restrict__ offs, int* __restrict__ cur, int n){
  int i = blockIdx.x * blockDim.x + threadIdx.x;
  if (i < n) cur[i] = offs[i];
}

__global__ void scatter_kernel(const int* __restrict__ row, const int* __restrict__ col,
                               int* __restrict__ cur, int* __restrict__ ecol, int E){
  int e = blockIdx.x * blockDim.x + threadIdx.x;
  if (e < E){
    int p = atomicAdd(&cur[row[e]], 1);
    ecol[p] = col[e];
  }
}

// ---------------- layer-0 invnorm (x) ----------------

__global__ void invnorm128_kernel(const float* __restrict__ x, float* __restrict__ invn, int N){
  int n = blockIdx.x * 4 + (threadIdx.x >> 6);
  int lane = threadIdx.x & 63;
  if (n >= N) return;
  float2 a = ((const float2*)(x + (size_t)n * 128))[lane];
  float ss = a.x * a.x + a.y * a.y;
  for (int off = 32; off; off >>= 1) ss += __shfl_xor(ss, off);
  if (lane == 0) invn[n] = 1.0f / fmaxf(sqrtf(ss), 1e-12f);
}

// ---------------- fused attention: sim + rowsum/deg + wself + compact ----------------

template<int D>
__global__ void att_kernel(const float* __restrict__ x, const float* __restrict__ invn,
                           const int* __restrict__ offs, const int* __restrict__ ecol,
                           float* __restrict__ simcsr,
                           float* __restrict__ wcomp, int* __restrict__ ccomp,
                           int* __restrict__ ncnt, float* __restrict__ wself, int N){
  // one block (4 waves) per node
  __shared__ __align__(16) float xs[D];
  __shared__ float rowsum_s;
  __shared__ int   deg_s;
  __shared__ float inv_s;
  int n = blockIdx.x;
  int tid = threadIdx.x;
  int wave = tid >> 6, lane = tid & 63;
  if (tid == 0){ rowsum_s = 0.0f; deg_s = 0; }
  int s = offs[n], e_end = offs[n + 1];
  float inr = invn[n];
  for (int i = tid; i < D; i += 256) xs[i] = x[(size_t)n * D + i] * inr;
  __syncthreads();
  // phase A: per-wave edge dot products
  for (int k = s + wave; k < e_end; k += 4){
    int c = ecol[k];
    float sdot;
    if constexpr (D == 256){
      float4 b = ((const float4*)(x + (size_t)c * D))[lane];
      float4 a = ((const float4*)xs)[lane];
      sdot = a.x * b.x + a.y * b.y + a.z * b.z + a.w * b.w;
    } else {
      float2 b = ((const float2*)(x + (size_t)c * D))[lane];
      float2 a = ((const float2*)xs)[lane];
      sdot = a.x * b.x + a.y * b.y;
    }
    for (int off = 32; off; off >>= 1) sdot += __shfl_xor(sdot, off);
    if (lane == 0){
      sdot *= invn[c];
      if (sdot < 0.1f) sdot = 0.0f;      // threshold; survivors > 0
      simcsr[k] = sdot;
      if (sdot != 0.0f){
        atomicAdd(&rowsum_s, sdot);
        atomicAdd(&deg_s, 1);
      }
    }
  }
  __syncthreads();
  if (tid == 0){
    float rs = rowsum_s;
    inv_s = (rs > 0.0f) ? 1.0f / rs : 0.0f;
    wself[n] = expf(1.0f / (float)(deg_s + 1));
    deg_s = 0;                           // reuse as compaction cursor
  }
  __syncthreads();
  // phase B: compact surviving edges to front of segment
  for (int k = s + tid; k < e_end; k += 256){
    float sv = simcsr[k];
    int  cv = ecol[k];
    if (sv > 0.0f){
      int p = atomicAdd(&deg_s, 1);
      wcomp[s + p] = expf(sv * inv_s);
      ccomp[s + p] = cv;
    }
  }
  __syncthreads();
  if (tid == 0) ncnt[n] = deg_s;
}

// ---------------- projection z = einsum('nd,hdo->nho') ----------------

template<int D>
__global__ void proj_kernel(const float* __restrict__ x, const float* __restrict__ W,
                            float* __restrict__ z, int N){
  // block = 256 threads, 8 nodes per block, 256 outputs (4 heads x 64)
  __shared__ float xs[8][D];
  int tid = threadIdx.x;
  int n0 = blockIdx.x * 8;
  for (int i = tid; i < 8 * D; i += 256){
    int nl = i / D, d = i % D;
    int n = n0 + nl;
    xs[nl][d] = (n < N) ? x[(size_t)n * D + d] : 0.0f;
  }
  __syncthreads();
  int h = tid >> 6, o = tid & 63;
  const float* Wp = W + (size_t)h * D * 64 + o;
  float acc[8];
  #pragma unroll
  for (int i = 0; i < 8; i++) acc[i] = 0.0f;
  for (int d = 0; d < D; d++){
    float w = Wp[(size_t)d * 64];
    #pragma unroll
    for (int i = 0; i < 8; i++) acc[i] += xs[i][d] * w;
  }
  #pragma unroll
  for (int i = 0; i < 8; i++){
    int n = n0 + i;
    if (n < N) z[(size_t)n * 256 + tid] = acc[i];
  }
}

__global__ void proj16_kernel(const float* __restrict__ x, const float* __restrict__ W,
                              float* __restrict__ z, int N){
  // layer 2: D=256, 16 outputs. 16 nodes x 16 outputs per block
  __shared__ float xs[16][256];   // 16 KB
  __shared__ float wsh[256 * 16]; // 16 KB
  int tid = threadIdx.x;
  int n0 = blockIdx.x * 16;
  for (int i = tid; i < 16 * 256; i += 256){
    int nl = i >> 8, d = i & 255;
    int n = n0 + nl;
    xs[nl][d] = (n < N) ? x[(size_t)n * 256 + d] : 0.0f;
  }
  for (int i = tid; i < 256 * 16; i += 256) wsh[i] = W[i];
  __syncthreads();
  int nl = tid >> 4, o = tid & 15;
  float acc = 0.0f;
  for (int d = 0; d < 256; d++) acc += xs[nl][d] * wsh[d * 16 + o];
  int n = n0 + nl;
  if (n < N) z[(size_t)n * 16 + o] = acc;
}

// ---------------- aggregation (compacted edges) + fused next-layer invnorm ----------------

template<bool ACT, bool NORM>
__global__ void agg256_kernel(const float* __restrict__ z, const float* __restrict__ wcomp,
                              const int* __restrict__ ccomp, const float* __restrict__ wself,
                              const int* __restrict__ offs, const int* __restrict__ ncnt,
                              float* __restrict__ out, float* __restrict__ invn, int N){
  // one block per node; thread t owns output channel t
  int n = blockIdx.x;
  int tid = threadIdx.x;
  int s = offs[n];
  int cnt = ncnt[n];
  float acc = wself[n] * z[(size_t)n * 256 + tid];
  for (int k = s; k < s + cnt; k++){
    float w = wcomp[k];
    int   c = ccomp[k];
    acc += w * z[(size_t)c * 256 + tid];
  }
  if (ACT) acc = (acc > 0.0f) ? acc : 0.01f * acc;
  out[(size_t)n * 256 + tid] = acc;
  if (NORM){
    __shared__ float red[4];
    float ss = acc * acc;
    for (int off = 32; off; off >>= 1) ss += __shfl_xor(ss, off);
    if ((tid & 63) == 0) red[tid >> 6] = ss;
    __syncthreads();
    if (tid == 0){
      float t = red[0] + red[1] + red[2] + red[3];
      invn[n] = 1.0f / fmaxf(sqrtf(t), 1e-12f);
    }
  }
}

__global__ void agg16_kernel(const float* __restrict__ z, const float* __restrict__ wcomp,
                             const int* __restrict__ ccomp, const float* __restrict__ wself,
                             const int* __restrict__ offs, const int* __restrict__ ncnt,
                             float* __restrict__ out, int N){
  int tid = threadIdx.x;
  int n = blockIdx.x * 16 + (tid >> 4);
  int o = tid & 15;
  if (n >= N) return;
  float acc = wself[n] * z[(size_t)n * 16 + o];
  int s = offs[n], cnt = ncnt[n];
  for (int k = s; k < s + cnt; k++){
    acc += wcomp[k] * z[(size_t)ccomp[k] * 16 + o];
  }
  out[(size_t)n * 16 + o] = acc;  // no activation on last layer
}

// ---------------- launch ----------------

extern "C" void kernel_launch(void* const* d_in, const int* in_sizes, int n_in,
                              void* d_out, int out_size, void* d_ws, size_t ws_size,
                              hipStream_t stream){
  const float* x  = (const float*)d_in[0];
  const float* W0 = (const float*)d_in[1];
  const float* W1 = (const float*)d_in[2];
  const float* W2 = (const float*)d_in[3];
  const int*   row = (const int*)d_in[4];
  const int*   col = (const int*)d_in[5];
  const int N = in_sizes[0] / 128;
  const int E = in_sizes[4];
  float* out = (float*)d_out;

  // workspace carve-up (~116 MB)
  float* p = (float*)d_ws;
  float* hbuf   = p; p += (size_t)N * 256;
  float* zbuf   = p; p += (size_t)N * 256;
  float* simcsr = p; p += E;
  float* wcomp  = p; p += E;
  float* wselfb = p; p += N;
  float* invn   = p; p += N;
  int* cnt  = (int*)p;
  int* offs = cnt + N;
  int* cur  = offs + N + 1;
  int* ecol = cur + N;
  int* ccomp = ecol + E;
  int* ncnt  = ccomp + E;

  // ---- CSR build (row/col static per call) ----
  hipMemsetAsync(cnt, 0, sizeof(int) * N, stream);
  count_kernel<<<cdiv(E, 256), 256, 0, stream>>>(row, cnt, E);
  scan_kernel<<<1, 1024, 0, stream>>>(cnt, offs, N);
  initcur_kernel<<<cdiv(N, 256), 256, 0, stream>>>(offs, cur, N);
  scatter_kernel<<<cdiv(E, 256), 256, 0, stream>>>(row, col, cur, ecol, E);

  // ---- Layer 0: in=x (D=128), W0[4,128,64], act ----
  invnorm128_kernel<<<cdiv(N, 4), 256, 0, stream>>>(x, invn, N);
  att_kernel<128><<<N, 256, 0, stream>>>(x, invn, offs, ecol, simcsr,
                                         wcomp, ccomp, ncnt, wselfb, N);
  proj_kernel<128><<<cdiv(N, 8), 256, 0, stream>>>(x, W0, zbuf, N);
  agg256_kernel<true, true><<<N, 256, 0, stream>>>(zbuf, wcomp, ccomp, wselfb,
                                                   offs, ncnt, hbuf, invn, N);

  // ---- Layer 1: in=hbuf (D=256), W1[4,256,64], act ----
  att_kernel<256><<<N, 256, 0, stream>>>(hbuf, invn, offs, ecol, simcsr,
                                         wcomp, ccomp, ncnt, wselfb, N);
  proj_kernel<256><<<cdiv(N, 8), 256, 0, stream>>>(hbuf, W1, zbuf, N);
  agg256_kernel<true, true><<<N, 256, 0, stream>>>(zbuf, wcomp, ccomp, wselfb,
                                                   offs, ncnt, hbuf, invn, N);

  // ---- Layer 2: in=hbuf (D=256), W2[1,256,16], no act, out=d_out ----
  att_kernel<256><<<N, 256, 0, stream>>>(hbuf, invn, offs, ecol, simcsr,
                                         wcomp, ccomp, ncnt, wselfb, N);
  proj16_kernel<<<cdiv(N, 16), 256, 0, stream>>>(hbuf, W2, zbuf, N);
  agg16_kernel<<<cdiv(N, 16), 256, 0, stream>>>(zbuf, wcomp, ccomp, wselfb,
                                                offs, ncnt, out, N);
}

// Round 3
// 1018.228 us; speedup vs baseline: 1.4968x; 1.2664x over previous
//
#include <hip/hip_runtime.h>
#include <math.h>

// GATGuard: 3-layer GAT, cosine-sim attention (thresh 0.1), L1 row norm,
// exp weights, degree self-loop. fp32. N=50000, E=800000, 128->256->256->16.
//
// R3: aggregation moved to input space (commutes with projection), fused with
// attention into one per-node kernel (phase A: sims, phase B: L2-hot weighted
// accumulate with LDS survivor compaction). Projection runs after aggregation
// with fused leaky-ReLU + next-layer invnorm. Last layer aggregates z (16-d).

static inline int cdiv(int a, int b){ return (a + b - 1) / b; }

// ---------------- CSR build (from row[]/col[]) ----------------

__global__ void count_kernel(const int* __restrict__ row, int* __restrict__ cnt, int E){
  int e = blockIdx.x * blockDim.x + threadIdx.x;
  if (e < E) atomicAdd(&cnt[row[e]], 1);
}

__global__ void scan_kernel(const int* __restrict__ cnt, int* __restrict__ offs, int n){
  __shared__ int tmp[1024];
  __shared__ int carry_s;
  int tid = threadIdx.x;
  if (tid == 0) carry_s = 0;
  __syncthreads();
  for (int base = 0; base < n; base += 1024){
    int v = (base + tid < n) ? cnt[base + tid] : 0;
    tmp[tid] = v;
    __syncthreads();
    for (int off = 1; off < 1024; off <<= 1){
      int t = (tid >= off) ? tmp[tid - off] : 0;
      __syncthreads();
      tmp[tid] += t;
      __syncthreads();
    }
    if (base + tid < n) offs[base + tid] = carry_s + tmp[tid] - v;  // exclusive
    __syncthreads();
    if (tid == 0) carry_s += tmp[1023];
    __syncthreads();
  }
  if (tid == 0) offs[n] = carry_s;
}

__global__ void initcur_kernel(const int* __restrict__ offs, int* __restrict__ cur, int n){
  int i = blockIdx.x * blockDim.x + threadIdx.x;
  if (i < n) cur[i] = offs[i];
}

__global__ void scatter_kernel(const int* __restrict__ row, const int* __restrict__ col,
                               int* __restrict__ cur, int* __restrict__ ecol, int E){
  int e = blockIdx.x * blockDim.x + threadIdx.x;
  if (e < E){
    int p = atomicAdd(&cur[row[e]], 1);
    ecol[p] = col[e];
  }
}

// ---------------- layer-0 invnorm (x) ----------------

__global__ void invnorm128_kernel(const float* __restrict__ x, float* __restrict__ invn, int N){
  int n = blockIdx.x * 4 + (threadIdx.x >> 6);
  int lane = threadIdx.x & 63;
  if (n >= N) return;
  float2 a = ((const float2*)(x + (size_t)n * 128))[lane];
  float ss = a.x * a.x + a.y * a.y;
  for (int off = 32; off; off >>= 1) ss += __shfl_xor(ss, off);
  if (lane == 0) invn[n] = 1.0f / fmaxf(sqrtf(ss), 1e-12f);
}

// ---------------- fused attention + input-space aggregation ----------------
// D   = feature dim for similarity (x rows)
// ZD  = dim of the array being aggregated (zagg rows); out is N x ZD.
template<int D, int ZD>
__global__ void fused_att_agg(const float* __restrict__ x, const float* __restrict__ invn,
                              const int* __restrict__ offs, const int* __restrict__ ecol,
                              float* __restrict__ simcsr, const float* __restrict__ zagg,
                              float* __restrict__ out, int N){
  __shared__ __align__(16) float xs[D];
  __shared__ float wv[256];
  __shared__ int   cv[256];
  __shared__ float red[256];
  __shared__ float rowsum_s;
  __shared__ int   deg_s;
  __shared__ int   cnt2_s;
  __shared__ float inv_s, wself_s;
  const int n = blockIdx.x;
  const int tid = threadIdx.x;
  const int wave = tid >> 6, lane = tid & 63;
  if (tid == 0){ rowsum_s = 0.0f; deg_s = 0; cnt2_s = 0; }
  const int s = offs[n], e = offs[n + 1];
  const float inr = invn[n];
  for (int i = tid; i < D; i += 256) xs[i] = x[(size_t)n * D + i];
  __syncthreads();

  // ---- phase A: per-edge cosine sims (2 edges in flight per wave) ----
  if constexpr (D == 256){
    float4 a = ((const float4*)xs)[lane];
    int k = s + wave;
    for (; k + 4 < e; k += 8){
      int c0 = ecol[k], c1 = ecol[k + 4];
      float4 b0 = ((const float4*)(x + (size_t)c0 * 256))[lane];
      float4 b1 = ((const float4*)(x + (size_t)c1 * 256))[lane];
      float d0 = a.x*b0.x + a.y*b0.y + a.z*b0.z + a.w*b0.w;
      float d1 = a.x*b1.x + a.y*b1.y + a.z*b1.z + a.w*b1.w;
      for (int off = 32; off; off >>= 1){ d0 += __shfl_xor(d0, off); d1 += __shfl_xor(d1, off); }
      if (lane == 0){
        d0 *= inr * invn[c0];
        d1 *= inr * invn[c1];
        if (d0 < 0.1f) d0 = 0.0f;
        if (d1 < 0.1f) d1 = 0.0f;
        simcsr[k] = d0; simcsr[k + 4] = d1;
        int dg = (d0 != 0.0f) + (d1 != 0.0f);
        if (dg){ atomicAdd(&rowsum_s, d0 + d1); atomicAdd(&deg_s, dg); }
      }
    }
    if (k < e){
      int c0 = ecol[k];
      float4 b0 = ((const float4*)(x + (size_t)c0 * 256))[lane];
      float d0 = a.x*b0.x + a.y*b0.y + a.z*b0.z + a.w*b0.w;
      for (int off = 32; off; off >>= 1) d0 += __shfl_xor(d0, off);
      if (lane == 0){
        d0 *= inr * invn[c0];
        if (d0 < 0.1f) d0 = 0.0f;
        simcsr[k] = d0;
        if (d0 != 0.0f){ atomicAdd(&rowsum_s, d0); atomicAdd(&deg_s, 1); }
      }
    }
  } else { // D == 128: 2 edges per wave (32 lanes x float4 each), x2 in flight
    const int half = lane >> 5, hl = lane & 31;
    float4 a = ((const float4*)xs)[hl];
    int k = s + wave * 2 + half;
    for (; k + 8 < e; k += 16){
      int c0 = ecol[k], c1 = ecol[k + 8];
      float4 b0 = ((const float4*)(x + (size_t)c0 * 128))[hl];
      float4 b1 = ((const float4*)(x + (size_t)c1 * 128))[hl];
      float d0 = a.x*b0.x + a.y*b0.y + a.z*b0.z + a.w*b0.w;
      float d1 = a.x*b1.x + a.y*b1.y + a.z*b1.z + a.w*b1.w;
      for (int off = 16; off; off >>= 1){ d0 += __shfl_xor(d0, off); d1 += __shfl_xor(d1, off); }
      if (hl == 0){
        d0 *= inr * invn[c0];
        d1 *= inr * invn[c1];
        if (d0 < 0.1f) d0 = 0.0f;
        if (d1 < 0.1f) d1 = 0.0f;
        simcsr[k] = d0; simcsr[k + 8] = d1;
        int dg = (d0 != 0.0f) + (d1 != 0.0f);
        if (dg){ atomicAdd(&rowsum_s, d0 + d1); atomicAdd(&deg_s, dg); }
      }
    }
    if (k < e){
      int c0 = ecol[k];
      float4 b0 = ((const float4*)(x + (size_t)c0 * 128))[hl];
      float d0 = a.x*b0.x + a.y*b0.y + a.z*b0.z + a.w*b0.w;
      for (int off = 16; off; off >>= 1) d0 += __shfl_xor(d0, off);
      if (hl == 0){
        d0 *= inr * invn[c0];
        if (d0 < 0.1f) d0 = 0.0f;
        simcsr[k] = d0;
        if (d0 != 0.0f){ atomicAdd(&rowsum_s, d0); atomicAdd(&deg_s, 1); }
      }
    }
  }
  __syncthreads();
  if (tid == 0){
    float rs = rowsum_s;
    inv_s = (rs > 0.0f) ? 1.0f / rs : 0.0f;
    wself_s = expf(1.0f / (float)(deg_s + 1));
  }
  __syncthreads();

  // ---- phase B: survivor-compacted weighted accumulate (rows L2-hot) ----
  constexpr int G = 256 / ZD;           // edge-parallel groups
  const int grp = tid / ZD, ch = tid % ZD;
  float acc = 0.0f;
  for (int base = s; base < e; base += 256){
    int k2 = base + tid;
    if (k2 < e){
      float sv = simcsr[k2];
      if (sv > 0.0f){
        int p = atomicAdd(&cnt2_s, 1);
        wv[p] = expf(sv * inv_s);
        cv[p] = ecol[k2];
      }
    }
    __syncthreads();
    int m = cnt2_s;
    #pragma unroll 4
    for (int t = grp; t < m; t += G)
      acc += wv[t] * zagg[(size_t)cv[t] * ZD + ch];
    __syncthreads();
    if (tid == 0) cnt2_s = 0;
    __syncthreads();
  }

  if constexpr (G == 1){
    out[(size_t)n * 256 + tid] = acc + wself_s * zagg[(size_t)n * 256 + tid];
  } else {
    red[tid] = acc;
    __syncthreads();
    for (int str = 128; str >= ZD; str >>= 1){
      if (tid < str) red[tid] += red[tid + str];
      __syncthreads();
    }
    if (tid < ZD)
      out[(size_t)n * ZD + tid] = red[tid] + wself_s * zagg[(size_t)n * ZD + tid];
  }
}

// ---------------- projection + leaky-ReLU + next-layer invnorm ----------------

template<int D>
__global__ void proj_act_norm(const float* __restrict__ xin, const float* __restrict__ W,
                              float* __restrict__ hout, float* __restrict__ invn, int N){
  // block = 256 threads, 8 nodes per block, 256 outputs (4 heads x 64)
  __shared__ float xs[8][D];
  __shared__ float red[4][8];
  int tid = threadIdx.x;
  int n0 = blockIdx.x * 8;
  for (int i = tid; i < 8 * D; i += 256){
    int nl = i / D, d = i % D;
    int n = n0 + nl;
    xs[nl][d] = (n < N) ? xin[(size_t)n * D + d] : 0.0f;
  }
  __syncthreads();
  int h = tid >> 6, o = tid & 63;
  const float* Wp = W + (size_t)h * D * 64 + o;
  float acc[8];
  #pragma unroll
  for (int i = 0; i < 8; i++) acc[i] = 0.0f;
  for (int d = 0; d < D; d++){
    float w = Wp[(size_t)d * 64];
    #pragma unroll
    for (int i = 0; i < 8; i++) acc[i] += xs[i][d] * w;
  }
  #pragma unroll
  for (int i = 0; i < 8; i++){
    float a = acc[i];
    acc[i] = (a > 0.0f) ? a : 0.01f * a;  // leaky relu
  }
  #pragma unroll
  for (int i = 0; i < 8; i++){
    int n = n0 + i;
    if (n < N) hout[(size_t)n * 256 + tid] = acc[i];
  }
  // fused invnorm of the activated output rows
  int wave = tid >> 6, lane = tid & 63;
  #pragma unroll
  for (int i = 0; i < 8; i++){
    float ss = acc[i] * acc[i];
    for (int off = 32; off; off >>= 1) ss += __shfl_xor(ss, off);
    if (lane == 0) red[wave][i] = ss;
  }
  __syncthreads();
  if (tid < 8){
    int n = n0 + tid;
    if (n < N){
      float t = red[0][tid] + red[1][tid] + red[2][tid] + red[3][tid];
      invn[n] = 1.0f / fmaxf(sqrtf(t), 1e-12f);
    }
  }
}

__global__ void proj16_kernel(const float* __restrict__ x, const float* __restrict__ W,
                              float* __restrict__ z, int N){
  // layer 2: D=256, 16 outputs. 16 nodes x 16 outputs per block
  __shared__ float xs[16][256];   // 16 KB
  __shared__ float wsh[256 * 16]; // 16 KB
  int tid = threadIdx.x;
  int n0 = blockIdx.x * 16;
  for (int i = tid; i < 16 * 256; i += 256){
    int nl = i >> 8, d = i & 255;
    int n = n0 + nl;
    xs[nl][d] = (n < N) ? x[(size_t)n * 256 + d] : 0.0f;
  }
  for (int i = tid; i < 256 * 16; i += 256) wsh[i] = W[i];
  __syncthreads();
  int nl = tid >> 4, o = tid & 15;
  float acc = 0.0f;
  for (int d = 0; d < 256; d++) acc += xs[nl][d] * wsh[d * 16 + o];
  int n = n0 + nl;
  if (n < N) z[(size_t)n * 16 + o] = acc;
}

// ---------------- launch ----------------

extern "C" void kernel_launch(void* const* d_in, const int* in_sizes, int n_in,
                              void* d_out, int out_size, void* d_ws, size_t ws_size,
                              hipStream_t stream){
  const float* x  = (const float*)d_in[0];
  const float* W0 = (const float*)d_in[1];
  const float* W1 = (const float*)d_in[2];
  const float* W2 = (const float*)d_in[3];
  const int*   row = (const int*)d_in[4];
  const int*   col = (const int*)d_in[5];
  const int N = in_sizes[0] / 128;
  const int E = in_sizes[4];
  float* out = (float*)d_out;

  // workspace carve-up (~113 MB)
  float* p = (float*)d_ws;
  float* hbuf   = p; p += (size_t)N * 256;
  float* aggbuf = p; p += (size_t)N * 256;
  float* z2     = p; p += (size_t)N * 16;
  float* simcsr = p; p += E;
  float* invn   = p; p += N;
  int* cnt  = (int*)p;
  int* offs = cnt + N;
  int* cur  = offs + N + 1;
  int* ecol = cur + N;

  // ---- CSR build (row/col static per call) ----
  hipMemsetAsync(cnt, 0, sizeof(int) * N, stream);
  count_kernel<<<cdiv(E, 256), 256, 0, stream>>>(row, cnt, E);
  scan_kernel<<<1, 1024, 0, stream>>>(cnt, offs, N);
  initcur_kernel<<<cdiv(N, 256), 256, 0, stream>>>(offs, cur, N);
  scatter_kernel<<<cdiv(E, 256), 256, 0, stream>>>(row, col, cur, ecol, E);

  // ---- Layer 0: sims on x (D=128), aggregate x, then project W0 + act + norm ----
  invnorm128_kernel<<<cdiv(N, 4), 256, 0, stream>>>(x, invn, N);
  fused_att_agg<128, 128><<<N, 256, 0, stream>>>(x, invn, offs, ecol, simcsr, x, aggbuf, N);
  proj_act_norm<128><<<cdiv(N, 8), 256, 0, stream>>>(aggbuf, W0, hbuf, invn, N);

  // ---- Layer 1: sims on h (D=256), aggregate h, then project W1 + act + norm ----
  fused_att_agg<256, 256><<<N, 256, 0, stream>>>(hbuf, invn, offs, ecol, simcsr, hbuf, aggbuf, N);
  proj_act_norm<256><<<cdiv(N, 8), 256, 0, stream>>>(aggbuf, W1, hbuf, invn, N);

  // ---- Layer 2: z2 = h.W2 (16-d), sims on h, aggregate z2 -> out ----
  proj16_kernel<<<cdiv(N, 16), 256, 0, stream>>>(hbuf, W2, z2, N);
  fused_att_agg<256, 16><<<N, 256, 0, stream>>>(hbuf, invn, offs, ecol, simcsr, z2, out, N);
}